// Round 4
// baseline (1985.314 us; speedup 1.0000x reference)
//
#include <hip/hip_runtime.h>
#include <hip/hip_bf16.h>

typedef __attribute__((ext_vector_type(8))) short short8;   // bf16x8 frag (4 VGPR)
typedef __attribute__((ext_vector_type(4))) float floatx4;  // mfma acc / fp32 vec
typedef __attribute__((ext_vector_type(4))) int intx4;
typedef __attribute__((ext_vector_type(4))) unsigned short ushortx4;

#define NB 4
#define EPS 1e-5f

// spconv binning geometry
#define TILE_ROWS 64
#define TILE_SHIFT 6
#define BIN_CAP 96        // Poisson(32): P(>96) ~ 1e-18/bin; guarded anyway
#define PF 3              // pipelined chunks (covers cnt<=48, 99.7% of bins)
#define TROW_STRIDE 68    // LDS row pitch in floats (pad: spreads banks across rows)

static __device__ __forceinline__ float bf2f(unsigned short h) {
  unsigned int u = ((unsigned int)h) << 16;
  return __builtin_bit_cast(float, u);
}
static __device__ __forceinline__ unsigned short f2bf(float f) {
  unsigned int u = __builtin_bit_cast(unsigned int, f);
  u += 0x7fffu + ((u >> 16) & 1u);
  return (unsigned short)(u >> 16);
}

// Native LDS float atomic-add, no return, NO memory clobber: data deps via "v"
// keep it after the accr compute; volatile-asm program order keeps it before the
// explicit lgkmcnt drain + barrier. No clobber -> compiler may hoist subsequent
// loads above it (restores memory-level parallelism).
static __device__ __forceinline__ void lds_fadd(float* p, float v) {
  unsigned off = (unsigned)(size_t)p;
  asm volatile("ds_add_f32 %0, %1" :: "v"(off), "v"(v));
}

// Swizzle fp32 W [batch][Kdim][Ncols] into bf16 MFMA B-fragment order:
// frag (b,s,t): lane l holds B[s*32 + (l>>4)*8 + j][t*16 + (l&15)], j=0..7.
__global__ void swizzle_w(const float* __restrict__ W,
                          unsigned short* __restrict__ out,
                          int Kdim, int Ncols, int batch) {
  int S = Kdim >> 5, T = Ncols >> 4;
  int total = batch * S * T * 64;
  int gid = blockIdx.x * blockDim.x + threadIdx.x;
  if (gid >= total) return;
  int l = gid & 63;
  int rest = gid >> 6;
  int t = rest % T; rest /= T;
  int s = rest % S; int b = rest / S;
  const float* Wb = W + (size_t)b * Kdim * Ncols;
  unsigned short* ob = out + (size_t)gid * 8;
  int kbase = s * 32 + (l >> 4) * 8;
  int n = t * 16 + (l & 15);
#pragma unroll
  for (int j = 0; j < 8; ++j) ob[j] = f2bf(Wb[(size_t)(kbase + j) * Ncols + n]);
}

// h1 (bf16, pre-norm) = feats[N,256](fp32) @ W1. Wave = 16 rows x 64 cols.
__launch_bounds__(256)
__global__ void gemm1(const float* __restrict__ feats,
                      const unsigned short* __restrict__ w1s,
                      unsigned short* __restrict__ h1, int N) {
  int wave = threadIdx.x >> 6;
  int l = threadIdx.x & 63;
  int r0 = blockIdx.x * 64 + wave * 16;
  const float* arow = feats + (size_t)(r0 + (l & 15)) * 256 + (l >> 4) * 8;
  floatx4 acc[4];
#pragma unroll
  for (int t = 0; t < 4; ++t) acc[t] = (floatx4){0.f, 0.f, 0.f, 0.f};
#pragma unroll
  for (int s = 0; s < 8; ++s) {
    floatx4 f0 = *(const floatx4*)(arow + s * 32);
    floatx4 f1 = *(const floatx4*)(arow + s * 32 + 4);
    short8 a;
#pragma unroll
    for (int j = 0; j < 4; ++j) { a[j] = (short)f2bf(f0[j]); a[j + 4] = (short)f2bf(f1[j]); }
#pragma unroll
    for (int t = 0; t < 4; ++t) {
      short8 b = *(const short8*)(w1s + ((size_t)(s * 4 + t) * 64 + l) * 8);
      acc[t] = __builtin_amdgcn_mfma_f32_16x16x32_bf16(a, b, acc[t], 0, 0, 0);
    }
  }
  int col0 = l & 15;
#pragma unroll
  for (int t = 0; t < 4; ++t)
#pragma unroll
    for (int reg = 0; reg < 4; ++reg) {
      int r = r0 + (l >> 4) * 4 + reg;
      h1[(size_t)r * 64 + t * 16 + col0] = f2bf(acc[t][reg]);
    }
}

// per-(instance,channel) sum/sumsq over bf16 [N,64] + row counts
__global__ void stats64_bf(const unsigned short* __restrict__ x,
                           const int* __restrict__ batch_idx,
                           float* __restrict__ sum, float* __restrict__ sq,
                           float* __restrict__ cnt, int N) {
  int c = threadIdx.x & 63;
  int rg = threadIdx.x >> 6;
  float s0 = 0, s1 = 0, s2 = 0, s3 = 0, q0 = 0, q1 = 0, q2 = 0, q3 = 0;
  float c0 = 0, c1 = 0, c2 = 0, c3 = 0;
  for (int i = blockIdx.x * 4 + rg; i < N; i += gridDim.x * 4) {
    int b = batch_idx[i];
    float v = bf2f(x[(size_t)i * 64 + c]);
    float v2 = v * v;
    if (b == 0) { s0 += v; q0 += v2; c0 += 1.f; }
    else if (b == 1) { s1 += v; q1 += v2; c1 += 1.f; }
    else if (b == 2) { s2 += v; q2 += v2; c2 += 1.f; }
    else { s3 += v; q3 += v2; c3 += 1.f; }
  }
  atomicAdd(&sum[0 * 64 + c], s0); atomicAdd(&sq[0 * 64 + c], q0);
  atomicAdd(&sum[1 * 64 + c], s1); atomicAdd(&sq[1 * 64 + c], q1);
  atomicAdd(&sum[2 * 64 + c], s2); atomicAdd(&sq[2 * 64 + c], q2);
  atomicAdd(&sum[3 * 64 + c], s3); atomicAdd(&sq[3 * 64 + c], q3);
  if (c == 0) {
    atomicAdd(&cnt[0], c0); atomicAdd(&cnt[1], c1);
    atomicAdd(&cnt[2], c2); atomicAdd(&cnt[3], c3);
  }
}

// per-(instance,channel) sum/sumsq over fp32 [N,256]
__global__ void stats256_f32(const float* __restrict__ y,
                             const int* __restrict__ batch_idx,
                             float* __restrict__ sum, float* __restrict__ sq, int N) {
  int c = threadIdx.x;  // 256 threads
  float s0 = 0, s1 = 0, s2 = 0, s3 = 0, q0 = 0, q1 = 0, q2 = 0, q3 = 0;
  for (int i = blockIdx.x; i < N; i += gridDim.x) {
    int b = batch_idx[i];
    float v = y[(size_t)i * 256 + c];
    float v2 = v * v;
    if (b == 0) { s0 += v; q0 += v2; }
    else if (b == 1) { s1 += v; q1 += v2; }
    else if (b == 2) { s2 += v; q2 += v2; }
    else { s3 += v; q3 += v2; }
  }
  atomicAdd(&sum[0 * 256 + c], s0); atomicAdd(&sq[0 * 256 + c], q0);
  atomicAdd(&sum[1 * 256 + c], s1); atomicAdd(&sq[1 * 256 + c], q1);
  atomicAdd(&sum[2 * 256 + c], s2); atomicAdd(&sq[2 * 256 + c], q2);
  atomicAdd(&sum[3 * 256 + c], s3); atomicAdd(&sq[3 * 256 + c], q3);
}

__global__ void finalize_stats(const float* __restrict__ sum, const float* __restrict__ sq,
                               const float* __restrict__ cnt, float* __restrict__ mean,
                               float* __restrict__ inv, int C) {
  int i = blockIdx.x * blockDim.x + threadIdx.x;
  if (i >= NB * C) return;
  int b = i / C;
  float n = cnt[b];
  float m = sum[i] / n;
  float v = sq[i] / n - m * m;
  mean[i] = m;
  inv[i] = rsqrtf(v + EPS);
}

// in-place: x = relu((x - mean)*inv), bf16 [N,64]
__global__ void norm64_bf_inplace(unsigned short* __restrict__ x,
                                  const int* __restrict__ batch_idx,
                                  const float* __restrict__ mean,
                                  const float* __restrict__ inv, int N) {
  size_t total = (size_t)N * 16;  // N*64/4
  for (size_t i = (size_t)blockIdx.x * blockDim.x + threadIdx.x; i < total;
       i += (size_t)gridDim.x * blockDim.x) {
    size_t e = i * 4;
    int row = (int)(e >> 6);
    int c = (int)(e & 63);
    int b = batch_idx[row];
    ushortx4 v = *(const ushortx4*)(x + e);
    ushortx4 o;
#pragma unroll
    for (int j = 0; j < 4; ++j) {
      float t = (bf2f(v[j]) - mean[b * 64 + c + j]) * inv[b * 64 + c + j];
      o[j] = f2bf(t > 0.f ? t : 0.f);
    }
    *(ushortx4*)(x + e) = o;
  }
}

// out_bf16 = relu((x - mean)*inv), x fp32 [N,64]
__global__ void norm64_f32(const float* __restrict__ x, const int* __restrict__ batch_idx,
                           const float* __restrict__ mean, const float* __restrict__ inv,
                           unsigned short* __restrict__ out, int N) {
  size_t total = (size_t)N * 16;
  for (size_t i = (size_t)blockIdx.x * blockDim.x + threadIdx.x; i < total;
       i += (size_t)gridDim.x * blockDim.x) {
    size_t e = i * 4;
    int row = (int)(e >> 6);
    int c = (int)(e & 63);
    int b = batch_idx[row];
    floatx4 v = *(const floatx4*)(x + e);
    ushortx4 o;
#pragma unroll
    for (int j = 0; j < 4; ++j) {
      float t = (v[j] - mean[b * 64 + c + j]) * inv[b * 64 + c + j];
      o[j] = f2bf(t > 0.f ? t : 0.f);
    }
    *(ushortx4*)(out + e) = o;
  }
}

// Bin pairs by (output_tile, k). Record packs o_local (6b) | in_idx (18b).
__global__ void bin_pairs(const int* __restrict__ out_idx, const int* __restrict__ in_idx,
                          int* __restrict__ bin_cnt, int* __restrict__ bin_recs, int M) {
  int k = blockIdx.y;
  int m = blockIdx.x * blockDim.x + threadIdx.x;
  if (m >= M) return;
  size_t e = (size_t)k * M + m;
  int o = out_idx[e];
  int bin = (o >> TILE_SHIFT) * 27 + k;
  int pos = atomicAdd(&bin_cnt[bin], 1);
  if (pos < BIN_CAP)
    bin_recs[(size_t)bin * BIN_CAP + pos] = ((o & (TILE_ROWS - 1)) << 18) | in_idx[e];
}

// One chunk (16 pairs): MFMA + shfl-distributed scatter via ds_add_f32.
static __device__ __forceinline__ void chunk_compute_scatter(
    int r, short8 a0, short8 a1, const short8 (&bfrag)[2][4],
    float* tileacc, int c0, int cnt, int lane_m, int lg) {
  floatx4 accr[4];
#pragma unroll
  for (int t = 0; t < 4; ++t) {
    accr[t] = (floatx4){0.f, 0.f, 0.f, 0.f};
    accr[t] = __builtin_amdgcn_mfma_f32_16x16x32_bf16(a0, bfrag[0][t], accr[t], 0, 0, 0);
    accr[t] = __builtin_amdgcn_mfma_f32_16x16x32_bf16(a1, bfrag[1][t], accr[t], 0, 0, 0);
  }
  // records for pairs c0+lg*4+reg live in lanes (lg*4+reg) of this wave
  int rp[4];
#pragma unroll
  for (int reg = 0; reg < 4; ++reg) rp[reg] = __shfl(r, lg * 4 + reg, 64);
#pragma unroll
  for (int reg = 0; reg < 4; ++reg) {
    int p = c0 + lg * 4 + reg;
    if (p < cnt) {
      int olc = (rp[reg] >> 18) & (TILE_ROWS - 1);
      float* dst = &tileacc[olc * TROW_STRIDE + lane_m];
#pragma unroll
      for (int t = 0; t < 4; ++t) lds_fadd(dst + t * 16, accr[t][reg]);
    }
  }
}

// sparse conv: one block per 64-row output tile; fp32 accumulator tile in LDS.
// Wave w owns bins k==w (mod 4). Per bin: recs + gathers for up to PF chunks
// issued back-to-back (MLP), then compute+scatter. Single lgkmcnt drain before
// the final barrier. Tile written once, coalesced, stats fused.
__launch_bounds__(256)
__global__ void spconv_tile(const unsigned short* __restrict__ h1_bf,
                            const unsigned short* __restrict__ w2s,
                            const int* __restrict__ bin_cnt,
                            const int* __restrict__ bin_recs,
                            const int* __restrict__ batch_idx,
                            float* __restrict__ h2_pre,
                            float* __restrict__ sumB, float* __restrict__ sqB, int N) {
  __shared__ float tileacc[TILE_ROWS * TROW_STRIDE];  // 64*68*4 = 17408 B
  int tid = threadIdx.x;
  int tile = blockIdx.x;
  int r0 = tile * TILE_ROWS;
  floatx4 z4 = (floatx4){0.f, 0.f, 0.f, 0.f};
  for (int i = tid; i < TILE_ROWS * TROW_STRIDE / 4; i += 256)
    *(floatx4*)&tileacc[i * 4] = z4;
  __syncthreads();

  int wave = tid >> 6, l = tid & 63;
  int lane_m = l & 15, lg = l >> 4;
  short8 z8 = {0, 0, 0, 0, 0, 0, 0, 0};
  for (int k = wave; k < 27; k += 4) {
    int bin = tile * 27 + k;
    int cnt = bin_cnt[bin];
    cnt = cnt < BIN_CAP ? cnt : BIN_CAP;
    if (cnt == 0) continue;  // wave-uniform, no barrier inside loop
    const unsigned short* wk = w2s + (size_t)k * 4096;
    short8 bfrag[2][4];
#pragma unroll
    for (int s = 0; s < 2; ++s)
#pragma unroll
      for (int t = 0; t < 4; ++t)
        bfrag[s][t] = *(const short8*)(wk + ((size_t)(s * 4 + t) * 64 + l) * 8);
    const int* recs = bin_recs + (size_t)bin * BIN_CAP;

    // stage 1: all record loads for up to PF chunks
    int rr[PF];
#pragma unroll
    for (int cc = 0; cc < PF; ++cc) {
      int idx = cc * 16 + lane_m;
      rr[cc] = (idx < cnt) ? recs[idx] : 0;
    }
    // stage 2: all gathers (up to PF in flight per wave)
    short8 pa0[PF], pa1[PF];
#pragma unroll
    for (int cc = 0; cc < PF; ++cc) {
      pa0[cc] = z8; pa1[cc] = z8;
      int idx = cc * 16 + lane_m;
      if (idx < cnt) {
        int in = rr[cc] & 0x3FFFF;
        const unsigned short* arow = h1_bf + (size_t)in * 64 + lg * 8;
        pa0[cc] = *(const short8*)(arow);
        pa1[cc] = *(const short8*)(arow + 32);
      }
    }
    // stage 3: compute + scatter
#pragma unroll
    for (int cc = 0; cc < PF; ++cc)
      if (cc * 16 < cnt)
        chunk_compute_scatter(rr[cc], pa0[cc], pa1[cc], bfrag, tileacc,
                              cc * 16, cnt, lane_m, lg);
    // tail (cnt > PF*16, rare)
    for (int c0 = PF * 16; c0 < cnt; c0 += 16) {
      int idx = c0 + lane_m;
      int r = (idx < cnt) ? recs[idx] : 0;
      short8 a0 = z8, a1 = z8;
      if (idx < cnt) {
        int in = r & 0x3FFFF;
        const unsigned short* arow = h1_bf + (size_t)in * 64 + lg * 8;
        a0 = *(const short8*)(arow);
        a1 = *(const short8*)(arow + 32);
      }
      chunk_compute_scatter(r, a0, a1, bfrag, tileacc, c0, cnt, lane_m, lg);
    }
  }
  // drain our untracked ds_add_f32 ops once, then barrier
  asm volatile("s_waitcnt lgkmcnt(0)" ::: "memory");
  __syncthreads();

  // writeout (coalesced, each row once) + fused per-instance stats
  int rows = N - r0;
  rows = rows < TILE_ROWS ? rows : TILE_ROWS;
  int c = tid & 63;
  float s0 = 0, s1 = 0, s2 = 0, s3 = 0, q0 = 0, q1 = 0, q2 = 0, q3 = 0;
  for (int r = tid >> 6; r < rows; r += 4) {
    float v = tileacc[r * TROW_STRIDE + c];
    h2_pre[(size_t)(r0 + r) * 64 + c] = v;
    int b = batch_idx[r0 + r];
    float v2 = v * v;
    if (b == 0) { s0 += v; q0 += v2; }
    else if (b == 1) { s1 += v; q1 += v2; }
    else if (b == 2) { s2 += v; q2 += v2; }
    else { s3 += v; q3 += v2; }
  }
  int blo = batch_idx[r0], bhi = batch_idx[r0 + rows - 1];
  if (blo <= 0 && 0 <= bhi) { atomicAdd(&sumB[0 * 64 + c], s0); atomicAdd(&sqB[0 * 64 + c], q0); }
  if (blo <= 1 && 1 <= bhi) { atomicAdd(&sumB[1 * 64 + c], s1); atomicAdd(&sqB[1 * 64 + c], q1); }
  if (blo <= 2 && 2 <= bhi) { atomicAdd(&sumB[2 * 64 + c], s2); atomicAdd(&sqB[2 * 64 + c], q2); }
  if (blo <= 3 && 3 <= bhi) { atomicAdd(&sumB[3 * 64 + c], s3); atomicAdd(&sqB[3 * 64 + c], q3); }
}

// y[N,256] (fp32, pre-norm) = h2_bf[N,64] @ W3. Block: 16 rows; wave = 64 cols.
__launch_bounds__(256)
__global__ void gemm3(const unsigned short* __restrict__ h2_bf,
                      const unsigned short* __restrict__ w3s,
                      float* __restrict__ y, int N) {
  int wave = threadIdx.x >> 6;
  int l = threadIdx.x & 63;
  int r0 = blockIdx.x * 16;
  int n0 = wave * 64;
  const unsigned short* arow = h2_bf + (size_t)(r0 + (l & 15)) * 64 + (l >> 4) * 8;
  floatx4 acc[4];
#pragma unroll
  for (int t = 0; t < 4; ++t) acc[t] = (floatx4){0.f, 0.f, 0.f, 0.f};
#pragma unroll
  for (int s = 0; s < 2; ++s) {
    short8 a = *(const short8*)(arow + s * 32);
#pragma unroll
    for (int t = 0; t < 4; ++t) {
      short8 b = *(const short8*)(w3s + ((size_t)(s * 16 + wave * 4 + t) * 64 + l) * 8);
      acc[t] = __builtin_amdgcn_mfma_f32_16x16x32_bf16(a, b, acc[t], 0, 0, 0);
    }
  }
#pragma unroll
  for (int t = 0; t < 4; ++t)
#pragma unroll
    for (int reg = 0; reg < 4; ++reg) {
      int r = r0 + (l >> 4) * 4 + reg;
      y[(size_t)r * 256 + n0 + t * 16 + (l & 15)] = acc[t][reg];
    }
}

// out = relu((y - meanC)*invC + feats), fp32 [N,256]. Works both when y aliases
// out (in-place, same-position RMW per thread) and when y is separate.
__global__ void final_out(const float* __restrict__ y,
                          const float* __restrict__ feats,
                          const int* __restrict__ batch_idx,
                          const float* __restrict__ mean, const float* __restrict__ inv,
                          float* __restrict__ out, int N) {
  size_t total = (size_t)N * 64;  // N*256/4
  for (size_t i = (size_t)blockIdx.x * blockDim.x + threadIdx.x; i < total;
       i += (size_t)gridDim.x * blockDim.x) {
    size_t e = i * 4;
    int row = (int)(e >> 8);
    int c = (int)(e & 255);
    int b = batch_idx[row];
    floatx4 yv = *(const floatx4*)(y + e);
    floatx4 fv = *(const floatx4*)(feats + e);
    floatx4 o;
#pragma unroll
    for (int j = 0; j < 4; ++j) {
      float t = (yv[j] - mean[b * 256 + c + j]) * inv[b * 256 + c + j] + fv[j];
      o[j] = t > 0.f ? t : 0.f;
    }
    *(floatx4*)(out + e) = o;
  }
}

extern "C" void kernel_launch(void* const* d_in, const int* in_sizes, int n_in,
                              void* d_out, int out_size, void* d_ws, size_t ws_size,
                              hipStream_t stream) {
  (void)n_in; (void)out_size;
  const float* feats = (const float*)d_in[0];
  const float* W1 = (const float*)d_in[1];
  const float* W2 = (const float*)d_in[2];
  const float* W3 = (const float*)d_in[3];
  const int* in_idx = (const int*)d_in[4];
  const int* out_idx = (const int*)d_in[5];
  const int* batch_idx = (const int*)d_in[6];
  int N = in_sizes[6];          // 200000
  int M = in_sizes[4] / 27;     // 100000

  int ntiles = (N + TILE_ROWS - 1) >> TILE_SHIFT;  // 3125
  int nbins = ntiles * 27;                         // 84375

  // ---- workspace ----
  char* base = (char*)d_ws;
  size_t off = 0;
  auto take = [&](size_t bytes) -> char* {
    char* p = base + off;
    off = (off + bytes + 255) & ~(size_t)255;
    return p;
  };
  float* zstat = (float*)take(3076 * sizeof(float));
  float* cnt = zstat;
  float* sumA = zstat + 4;   float* sqA = sumA + 256;
  float* sumB = sqA + 256;   float* sqB = sumB + 256;
  float* sumC = sqB + 256;   float* sqC = sumC + 1024;
  float* meanA = (float*)take(3072 * sizeof(float));
  float* invA = meanA + 256;
  float* meanB = invA + 256; float* invB = meanB + 256;
  float* meanC = invB + 256; float* invC = meanC + 1024;
  int* bin_cnt = (int*)take((size_t)nbins * sizeof(int));  // 337.5 KB
  unsigned short* w1s = (unsigned short*)take(16384 * 2);
  unsigned short* w2s = (unsigned short*)take(110592 * 2);
  unsigned short* w3s = (unsigned short*)take(16384 * 2);
  unsigned short* h1_bf = (unsigned short*)take((size_t)N * 64 * 2);  // 25.6 MB
  unsigned short* h2_bf = (unsigned short*)take((size_t)N * 64 * 2);  // 25.6 MB

  // Big buffers: prefer d_ws if it is large enough (runtime branch); otherwise
  // fall back to carving d_out (204.8 MB fp32 output) as scratch:
  //   [0, N*64*4)           h2_pre  (dead before gemm3 rewrites d_out)
  //   [N*64*4, +recs_bytes) bin_recs (disjoint from h2_pre, also dead by gemm3)
  size_t recs_bytes  = (size_t)nbins * BIN_CAP * sizeof(int);   // 32.4 MB
  size_t h2pre_bytes = (size_t)N * 64 * sizeof(float);          // 51.2 MB
  size_t y_bytes     = (size_t)N * 256 * sizeof(float);         // 204.8 MB
  char* dout = (char*)d_out;
  float* h2_pre  = (float*)dout;
  int* bin_recs  = (int*)(dout + h2pre_bytes);
  float* y       = (float*)dout;
  if (ws_size >= off + recs_bytes + 256)  bin_recs = (int*)take(recs_bytes);
  if (ws_size >= off + h2pre_bytes + 256) h2_pre   = (float*)take(h2pre_bytes);
  if (ws_size >= off + y_bytes + 256)     y        = (float*)take(y_bytes);

  hipMemsetAsync(zstat, 0, 3076 * sizeof(float), stream);
  hipMemsetAsync(bin_cnt, 0, (size_t)nbins * sizeof(int), stream);

  swizzle_w<<<8, 256, 0, stream>>>(W1, w1s, 256, 64, 1);
  swizzle_w<<<54, 256, 0, stream>>>(W2, w2s, 64, 64, 27);
  swizzle_w<<<8, 256, 0, stream>>>(W3, w3s, 64, 256, 1);

  bin_pairs<<<dim3((M + 255) / 256, 27), 256, 0, stream>>>(out_idx, in_idx,
                                                           bin_cnt, bin_recs, M);

  gemm1<<<N / 64, 256, 0, stream>>>(feats, w1s, h1_bf, N);
  stats64_bf<<<256, 256, 0, stream>>>(h1_bf, batch_idx, sumA, sqA, cnt, N);
  finalize_stats<<<1, 256, 0, stream>>>(sumA, sqA, cnt, meanA, invA, 64);
  norm64_bf_inplace<<<1024, 256, 0, stream>>>(h1_bf, batch_idx, meanA, invA, N);

  spconv_tile<<<ntiles, 256, 0, stream>>>(h1_bf, w2s, bin_cnt, bin_recs,
                                          batch_idx, h2_pre, sumB, sqB, N);
  finalize_stats<<<1, 256, 0, stream>>>(sumB, sqB, cnt, meanB, invB, 64);
  norm64_f32<<<1024, 256, 0, stream>>>(h2_pre, batch_idx, meanB, invB, h2_bf, N);

  gemm3<<<N / 16, 256, 0, stream>>>(h2_bf, w3s, y, N);
  stats256_f32<<<512, 256, 0, stream>>>(y, batch_idx, sumC, sqC, N);
  finalize_stats<<<4, 256, 0, stream>>>(sumC, sqC, cnt, meanC, invC, 256);
  final_out<<<2048, 256, 0, stream>>>(y, feats, batch_idx, meanC, invC,
                                      (float*)d_out, N);
}

// Round 5
// 1293.056 us; speedup vs baseline: 1.5354x; 1.5354x over previous
//
#include <hip/hip_runtime.h>
#include <hip/hip_bf16.h>

typedef __attribute__((ext_vector_type(8))) short short8;   // bf16x8 frag (4 VGPR)
typedef __attribute__((ext_vector_type(4))) float floatx4;  // mfma acc / fp32 vec
typedef __attribute__((ext_vector_type(4))) int intx4;
typedef __attribute__((ext_vector_type(4))) unsigned short ushortx4;

#define NB 4
#define EPS 1e-5f

// spconv binning geometry: 32-row tiles, wave-private LDS accumulator
#define TILE_ROWS 32
#define TILE_SHIFT 5
#define BIN_CAP 64        // Poisson(16): P(>64) ~ 1e-24/bin; clamped anyway

static __device__ __forceinline__ float bf2f(unsigned short h) {
  unsigned int u = ((unsigned int)h) << 16;
  return __builtin_bit_cast(float, u);
}
static __device__ __forceinline__ unsigned short f2bf(float f) {
  unsigned int u = __builtin_bit_cast(unsigned int, f);
  u += 0x7fffu + ((u >> 16) & 1u);
  return (unsigned short)(u >> 16);
}

// Swizzle fp32 W [batch][Kdim][Ncols] into bf16 MFMA B-fragment order:
// frag (b,s,t): lane l holds B[s*32 + (l>>4)*8 + j][t*16 + (l&15)], j=0..7.
__global__ void swizzle_w(const float* __restrict__ W,
                          unsigned short* __restrict__ out,
                          int Kdim, int Ncols, int batch) {
  int S = Kdim >> 5, T = Ncols >> 4;
  int total = batch * S * T * 64;
  int gid = blockIdx.x * blockDim.x + threadIdx.x;
  if (gid >= total) return;
  int l = gid & 63;
  int rest = gid >> 6;
  int t = rest % T; rest /= T;
  int s = rest % S; int b = rest / S;
  const float* Wb = W + (size_t)b * Kdim * Ncols;
  unsigned short* ob = out + (size_t)gid * 8;
  int kbase = s * 32 + (l >> 4) * 8;
  int n = t * 16 + (l & 15);
#pragma unroll
  for (int j = 0; j < 8; ++j) ob[j] = f2bf(Wb[(size_t)(kbase + j) * Ncols + n]);
}

// h1 (bf16, pre-norm) = feats[N,256](fp32) @ W1. Wave = 16 rows x 64 cols.
__launch_bounds__(256)
__global__ void gemm1(const float* __restrict__ feats,
                      const unsigned short* __restrict__ w1s,
                      unsigned short* __restrict__ h1, int N) {
  int wave = threadIdx.x >> 6;
  int l = threadIdx.x & 63;
  int r0 = blockIdx.x * 64 + wave * 16;
  const float* arow = feats + (size_t)(r0 + (l & 15)) * 256 + (l >> 4) * 8;
  floatx4 acc[4];
#pragma unroll
  for (int t = 0; t < 4; ++t) acc[t] = (floatx4){0.f, 0.f, 0.f, 0.f};
#pragma unroll
  for (int s = 0; s < 8; ++s) {
    floatx4 f0 = *(const floatx4*)(arow + s * 32);
    floatx4 f1 = *(const floatx4*)(arow + s * 32 + 4);
    short8 a;
#pragma unroll
    for (int j = 0; j < 4; ++j) { a[j] = (short)f2bf(f0[j]); a[j + 4] = (short)f2bf(f1[j]); }
#pragma unroll
    for (int t = 0; t < 4; ++t) {
      short8 b = *(const short8*)(w1s + ((size_t)(s * 4 + t) * 64 + l) * 8);
      acc[t] = __builtin_amdgcn_mfma_f32_16x16x32_bf16(a, b, acc[t], 0, 0, 0);
    }
  }
  int col0 = l & 15;
#pragma unroll
  for (int t = 0; t < 4; ++t)
#pragma unroll
    for (int reg = 0; reg < 4; ++reg) {
      int r = r0 + (l >> 4) * 4 + reg;
      h1[(size_t)r * 64 + t * 16 + col0] = f2bf(acc[t][reg]);
    }
}

// per-(instance,channel) sum/sumsq over bf16 [N,64] + row counts
__global__ void stats64_bf(const unsigned short* __restrict__ x,
                           const int* __restrict__ batch_idx,
                           float* __restrict__ sum, float* __restrict__ sq,
                           float* __restrict__ cnt, int N) {
  int c = threadIdx.x & 63;
  int rg = threadIdx.x >> 6;
  float s0 = 0, s1 = 0, s2 = 0, s3 = 0, q0 = 0, q1 = 0, q2 = 0, q3 = 0;
  float c0 = 0, c1 = 0, c2 = 0, c3 = 0;
  for (int i = blockIdx.x * 4 + rg; i < N; i += gridDim.x * 4) {
    int b = batch_idx[i];
    float v = bf2f(x[(size_t)i * 64 + c]);
    float v2 = v * v;
    if (b == 0) { s0 += v; q0 += v2; c0 += 1.f; }
    else if (b == 1) { s1 += v; q1 += v2; c1 += 1.f; }
    else if (b == 2) { s2 += v; q2 += v2; c2 += 1.f; }
    else { s3 += v; q3 += v2; c3 += 1.f; }
  }
  atomicAdd(&sum[0 * 64 + c], s0); atomicAdd(&sq[0 * 64 + c], q0);
  atomicAdd(&sum[1 * 64 + c], s1); atomicAdd(&sq[1 * 64 + c], q1);
  atomicAdd(&sum[2 * 64 + c], s2); atomicAdd(&sq[2 * 64 + c], q2);
  atomicAdd(&sum[3 * 64 + c], s3); atomicAdd(&sq[3 * 64 + c], q3);
  if (c == 0) {
    atomicAdd(&cnt[0], c0); atomicAdd(&cnt[1], c1);
    atomicAdd(&cnt[2], c2); atomicAdd(&cnt[3], c3);
  }
}

// per-(instance,channel) sum/sumsq over fp32 [N,256]
__global__ void stats256_f32(const float* __restrict__ y,
                             const int* __restrict__ batch_idx,
                             float* __restrict__ sum, float* __restrict__ sq, int N) {
  int c = threadIdx.x;  // 256 threads
  float s0 = 0, s1 = 0, s2 = 0, s3 = 0, q0 = 0, q1 = 0, q2 = 0, q3 = 0;
  for (int i = blockIdx.x; i < N; i += gridDim.x) {
    int b = batch_idx[i];
    float v = y[(size_t)i * 256 + c];
    float v2 = v * v;
    if (b == 0) { s0 += v; q0 += v2; }
    else if (b == 1) { s1 += v; q1 += v2; }
    else if (b == 2) { s2 += v; q2 += v2; }
    else { s3 += v; q3 += v2; }
  }
  atomicAdd(&sum[0 * 256 + c], s0); atomicAdd(&sq[0 * 256 + c], q0);
  atomicAdd(&sum[1 * 256 + c], s1); atomicAdd(&sq[1 * 256 + c], q1);
  atomicAdd(&sum[2 * 256 + c], s2); atomicAdd(&sq[2 * 256 + c], q2);
  atomicAdd(&sum[3 * 256 + c], s3); atomicAdd(&sq[3 * 256 + c], q3);
}

__global__ void finalize_stats(const float* __restrict__ sum, const float* __restrict__ sq,
                               const float* __restrict__ cnt, float* __restrict__ mean,
                               float* __restrict__ inv, int C) {
  int i = blockIdx.x * blockDim.x + threadIdx.x;
  if (i >= NB * C) return;
  int b = i / C;
  float n = cnt[b];
  float m = sum[i] / n;
  float v = sq[i] / n - m * m;
  mean[i] = m;
  inv[i] = rsqrtf(v + EPS);
}

// in-place: x = relu((x - mean)*inv), bf16 [N,64]
__global__ void norm64_bf_inplace(unsigned short* __restrict__ x,
                                  const int* __restrict__ batch_idx,
                                  const float* __restrict__ mean,
                                  const float* __restrict__ inv, int N) {
  size_t total = (size_t)N * 16;  // N*64/4
  for (size_t i = (size_t)blockIdx.x * blockDim.x + threadIdx.x; i < total;
       i += (size_t)gridDim.x * blockDim.x) {
    size_t e = i * 4;
    int row = (int)(e >> 6);
    int c = (int)(e & 63);
    int b = batch_idx[row];
    ushortx4 v = *(const ushortx4*)(x + e);
    ushortx4 o;
#pragma unroll
    for (int j = 0; j < 4; ++j) {
      float t = (bf2f(v[j]) - mean[b * 64 + c + j]) * inv[b * 64 + c + j];
      o[j] = f2bf(t > 0.f ? t : 0.f);
    }
    *(ushortx4*)(x + e) = o;
  }
}

// out_bf16 = relu((x - mean)*inv), x fp32 [N,64]
__global__ void norm64_f32(const float* __restrict__ x, const int* __restrict__ batch_idx,
                           const float* __restrict__ mean, const float* __restrict__ inv,
                           unsigned short* __restrict__ out, int N) {
  size_t total = (size_t)N * 16;
  for (size_t i = (size_t)blockIdx.x * blockDim.x + threadIdx.x; i < total;
       i += (size_t)gridDim.x * blockDim.x) {
    size_t e = i * 4;
    int row = (int)(e >> 6);
    int c = (int)(e & 63);
    int b = batch_idx[row];
    floatx4 v = *(const floatx4*)(x + e);
    ushortx4 o;
#pragma unroll
    for (int j = 0; j < 4; ++j) {
      float t = (v[j] - mean[b * 64 + c + j]) * inv[b * 64 + c + j];
      o[j] = f2bf(t > 0.f ? t : 0.f);
    }
    *(ushortx4*)(out + e) = o;
  }
}

// Bin pairs by (output_tile, k). Record packs o_local (5b) | in_idx (18b).
__global__ void bin_pairs(const int* __restrict__ out_idx, const int* __restrict__ in_idx,
                          int* __restrict__ bin_cnt, int* __restrict__ bin_recs, int M) {
  int k = blockIdx.y;
  int m = blockIdx.x * blockDim.x + threadIdx.x;
  if (m >= M) return;
  size_t e = (size_t)k * M + m;
  int o = out_idx[e];
  int bin = (o >> TILE_SHIFT) * 27 + k;
  int pos = atomicAdd(&bin_cnt[bin], 1);
  if (pos < BIN_CAP)
    bin_recs[(size_t)bin * BIN_CAP + pos] = ((o & (TILE_ROWS - 1)) << 18) | in_idx[e];
}

// sparse conv, ZERO atomics: 1-wave blocks (64 thr), one 32-row output tile per
// block, fp32 accumulator tile private to the wave in LDS (8 KB). Per k-bin:
// gather up to 16 h1 rows, MFMA vs W2[k] frags, then per-pair shfl-redistribute
// the 64-ch result to all lanes and do a plain (non-atomic) LDS += — race-free
// because one wave owns the tile and pairs are applied one at a time.
// NOTE (r4 post-mortem): ds_add_f32 atomics are lane-serialized on gfx950
// (~930us for 172.8M lane-ops) — never bulk-scatter through LDS atomics.
__launch_bounds__(64)
__global__ void spconv_tile(const unsigned short* __restrict__ h1_bf,
                            const unsigned short* __restrict__ w2s,
                            const int* __restrict__ bin_cnt,
                            const int* __restrict__ bin_recs,
                            const int* __restrict__ batch_idx,
                            float* __restrict__ h2_pre,
                            float* __restrict__ sumB, float* __restrict__ sqB, int N) {
  __shared__ float tileacc[TILE_ROWS * 64];  // 8 KB, private to this 1-wave block
  int l = threadIdx.x;                        // 0..63
  int tile = blockIdx.x;
  int r0 = tile * TILE_ROWS;
  floatx4 z4 = (floatx4){0.f, 0.f, 0.f, 0.f};
#pragma unroll
  for (int i = 0; i < 8; ++i) *(floatx4*)&tileacc[i * 256 + l * 4] = z4;
  // no barrier needed: single wave; compiler orders same-wave LDS accesses.

  int lane_m = l & 15, lg = l >> 4;
  short8 z8 = {0, 0, 0, 0, 0, 0, 0, 0};
  for (int k = 0; k < 27; ++k) {
    int bin = tile * 27 + k;
    int cnt = bin_cnt[bin];
    cnt = cnt < BIN_CAP ? cnt : BIN_CAP;
    if (cnt == 0) continue;
    const unsigned short* wk = w2s + (size_t)k * 4096;
    short8 bfrag[2][4];
#pragma unroll
    for (int s = 0; s < 2; ++s)
#pragma unroll
      for (int t = 0; t < 4; ++t)
        bfrag[s][t] = *(const short8*)(wk + ((size_t)(s * 4 + t) * 64 + l) * 8);
    const int* recs = bin_recs + (size_t)bin * BIN_CAP;
    for (int c0 = 0; c0 < cnt; c0 += 16) {
      int nrem = cnt - c0;
      nrem = nrem < 16 ? nrem : 16;
      int idx = c0 + lane_m;
      int rr = 0;
      short8 a0 = z8, a1 = z8;
      if (idx < cnt) {
        rr = recs[idx];
        const unsigned short* arow = h1_bf + (size_t)(rr & 0x3FFFF) * 64 + lg * 8;
        a0 = *(const short8*)(arow);
        a1 = *(const short8*)(arow + 32);
      }
      floatx4 accr[4];
#pragma unroll
      for (int t = 0; t < 4; ++t) {
        accr[t] = (floatx4){0.f, 0.f, 0.f, 0.f};
        accr[t] = __builtin_amdgcn_mfma_f32_16x16x32_bf16(a0, bfrag[0][t], accr[t], 0, 0, 0);
        accr[t] = __builtin_amdgcn_mfma_f32_16x16x32_bf16(a1, bfrag[1][t], accr[t], 0, 0, 0);
      }
      // Per-pair scatter. Pair p result lives in lanes lg==p>>2, regs
      // accr[t][p&3] at channel (lane&15)+16t. Redistribute so lane l holds
      // channel l, then plain LDS RMW (no collisions: one pair at a time).
#pragma unroll
      for (int p = 0; p < 16; ++p) {
        int src = (l & 15) | ((p >> 2) << 4);
        float v0 = __shfl(accr[0][p & 3], src, 64);
        float v1 = __shfl(accr[1][p & 3], src, 64);
        float v2 = __shfl(accr[2][p & 3], src, 64);
        float v3 = __shfl(accr[3][p & 3], src, 64);
        float vlo = (l & 16) ? v1 : v0;
        float vhi = (l & 16) ? v3 : v2;
        float v = (l & 32) ? vhi : vlo;
        if (p < nrem) {  // wave-uniform
          int rec = __shfl(rr, p, 64);
          int olc = (rec >> 18) & (TILE_ROWS - 1);
          tileacc[olc * 64 + l] += v;
        }
      }
    }
  }

  // writeout (coalesced, each row once) + fused per-instance stats. c = l.
  int rows = N - r0;
  rows = rows < TILE_ROWS ? rows : TILE_ROWS;
  float s0 = 0, s1 = 0, s2 = 0, s3 = 0, q0 = 0, q1 = 0, q2 = 0, q3 = 0;
  for (int r = 0; r < rows; ++r) {
    float v = tileacc[r * 64 + l];
    h2_pre[(size_t)(r0 + r) * 64 + l] = v;
    int b = batch_idx[r0 + r];
    float v2 = v * v;
    if (b == 0) { s0 += v; q0 += v2; }
    else if (b == 1) { s1 += v; q1 += v2; }
    else if (b == 2) { s2 += v; q2 += v2; }
    else { s3 += v; q3 += v2; }
  }
  int blo = batch_idx[r0], bhi = batch_idx[r0 + rows - 1];
  if (blo <= 0 && 0 <= bhi) { atomicAdd(&sumB[0 * 64 + l], s0); atomicAdd(&sqB[0 * 64 + l], q0); }
  if (blo <= 1 && 1 <= bhi) { atomicAdd(&sumB[1 * 64 + l], s1); atomicAdd(&sqB[1 * 64 + l], q1); }
  if (blo <= 2 && 2 <= bhi) { atomicAdd(&sumB[2 * 64 + l], s2); atomicAdd(&sqB[2 * 64 + l], q2); }
  if (blo <= 3 && 3 <= bhi) { atomicAdd(&sumB[3 * 64 + l], s3); atomicAdd(&sqB[3 * 64 + l], q3); }
}

// y[N,256] (fp32, pre-norm) = h2_bf[N,64] @ W3. Block: 16 rows; wave = 64 cols.
__launch_bounds__(256)
__global__ void gemm3(const unsigned short* __restrict__ h2_bf,
                      const unsigned short* __restrict__ w3s,
                      float* __restrict__ y, int N) {
  int wave = threadIdx.x >> 6;
  int l = threadIdx.x & 63;
  int r0 = blockIdx.x * 16;
  int n0 = wave * 64;
  const unsigned short* arow = h2_bf + (size_t)(r0 + (l & 15)) * 64 + (l >> 4) * 8;
  floatx4 acc[4];
#pragma unroll
  for (int t = 0; t < 4; ++t) acc[t] = (floatx4){0.f, 0.f, 0.f, 0.f};
#pragma unroll
  for (int s = 0; s < 2; ++s) {
    short8 a = *(const short8*)(arow + s * 32);
#pragma unroll
    for (int t = 0; t < 4; ++t) {
      short8 b = *(const short8*)(w3s + ((size_t)(s * 16 + wave * 4 + t) * 64 + l) * 8);
      acc[t] = __builtin_amdgcn_mfma_f32_16x16x32_bf16(a, b, acc[t], 0, 0, 0);
    }
  }
#pragma unroll
  for (int t = 0; t < 4; ++t)
#pragma unroll
    for (int reg = 0; reg < 4; ++reg) {
      int r = r0 + (l >> 4) * 4 + reg;
      y[(size_t)r * 256 + n0 + t * 16 + (l & 15)] = acc[t][reg];
    }
}

// out = relu((y - meanC)*invC + feats), fp32 [N,256]; y aliases out (in-place,
// same-position RMW per thread -> race-free).
__global__ void final_out(const float* __restrict__ y,
                          const float* __restrict__ feats,
                          const int* __restrict__ batch_idx,
                          const float* __restrict__ mean, const float* __restrict__ inv,
                          float* __restrict__ out, int N) {
  size_t total = (size_t)N * 64;  // N*256/4
  for (size_t i = (size_t)blockIdx.x * blockDim.x + threadIdx.x; i < total;
       i += (size_t)gridDim.x * blockDim.x) {
    size_t e = i * 4;
    int row = (int)(e >> 8);
    int c = (int)(e & 255);
    int b = batch_idx[row];
    floatx4 yv = *(const floatx4*)(y + e);
    floatx4 fv = *(const floatx4*)(feats + e);
    floatx4 o;
#pragma unroll
    for (int j = 0; j < 4; ++j) {
      float t = (yv[j] - mean[b * 256 + c + j]) * inv[b * 256 + c + j] + fv[j];
      o[j] = t > 0.f ? t : 0.f;
    }
    *(floatx4*)(out + e) = o;
  }
}

extern "C" void kernel_launch(void* const* d_in, const int* in_sizes, int n_in,
                              void* d_out, int out_size, void* d_ws, size_t ws_size,
                              hipStream_t stream) {
  (void)n_in; (void)out_size; (void)ws_size;
  const float* feats = (const float*)d_in[0];
  const float* W1 = (const float*)d_in[1];
  const float* W2 = (const float*)d_in[2];
  const float* W3 = (const float*)d_in[3];
  const int* in_idx = (const int*)d_in[4];
  const int* out_idx = (const int*)d_in[5];
  const int* batch_idx = (const int*)d_in[6];
  int N = in_sizes[6];          // 200000
  int M = in_sizes[4] / 27;     // 100000

  int ntiles = (N + TILE_ROWS - 1) >> TILE_SHIFT;  // 6250
  int nbins = ntiles * 27;                         // 168750

  // ---- workspace (~53 MB) ----
  char* base = (char*)d_ws;
  size_t off = 0;
  auto take = [&](size_t bytes) -> char* {
    char* p = base + off;
    off = (off + bytes + 255) & ~(size_t)255;
    return p;
  };
  float* zstat = (float*)take(3076 * sizeof(float));
  float* cnt = zstat;
  float* sumA = zstat + 4;   float* sqA = sumA + 256;
  float* sumB = sqA + 256;   float* sqB = sumB + 256;
  float* sumC = sqB + 256;   float* sqC = sumC + 1024;
  float* meanA = (float*)take(3072 * sizeof(float));
  float* invA = meanA + 256;
  float* meanB = invA + 256; float* invB = meanB + 256;
  float* meanC = invB + 256; float* invC = meanC + 1024;
  int* bin_cnt = (int*)take((size_t)nbins * sizeof(int));  // 675 KB
  unsigned short* w1s = (unsigned short*)take(16384 * 2);
  unsigned short* w2s = (unsigned short*)take(110592 * 2);
  unsigned short* w3s = (unsigned short*)take(16384 * 2);
  unsigned short* h1_bf = (unsigned short*)take((size_t)N * 64 * 2);  // 25.6 MB
  unsigned short* h2_bf = (unsigned short*)take((size_t)N * 64 * 2);  // 25.6 MB

  // d_out (fp32, N*256 = 204.8 MB) doubles as scratch:
  //   [0, N*64*4)             h2_pre fp32 (written once by spconv_tile)
  //   [N*64*4, +nbins*256)    bin_recs (43.2 MB) — disjoint from h2_pre; both
  //                           dead before gemm3 overwrites all of d_out with y.
  float* h2_pre = (float*)d_out;
  int* bin_recs = (int*)((char*)d_out + (size_t)N * 64 * sizeof(float));
  float* y = (float*)d_out;

  hipMemsetAsync(zstat, 0, 3076 * sizeof(float), stream);
  hipMemsetAsync(bin_cnt, 0, (size_t)nbins * sizeof(int), stream);

  swizzle_w<<<8, 256, 0, stream>>>(W1, w1s, 256, 64, 1);
  swizzle_w<<<54, 256, 0, stream>>>(W2, w2s, 64, 64, 27);
  swizzle_w<<<8, 256, 0, stream>>>(W3, w3s, 64, 256, 1);

  bin_pairs<<<dim3((M + 255) / 256, 27), 256, 0, stream>>>(out_idx, in_idx,
                                                           bin_cnt, bin_recs, M);

  gemm1<<<N / 64, 256, 0, stream>>>(feats, w1s, h1_bf, N);
  stats64_bf<<<256, 256, 0, stream>>>(h1_bf, batch_idx, sumA, sqA, cnt, N);
  finalize_stats<<<1, 256, 0, stream>>>(sumA, sqA, cnt, meanA, invA, 64);
  norm64_bf_inplace<<<1024, 256, 0, stream>>>(h1_bf, batch_idx, meanA, invA, N);

  spconv_tile<<<ntiles, 64, 0, stream>>>(h1_bf, w2s, bin_cnt, bin_recs,
                                         batch_idx, h2_pre, sumB, sqB, N);
  finalize_stats<<<1, 256, 0, stream>>>(sumB, sqB, cnt, meanB, invB, 64);
  norm64_f32<<<1024, 256, 0, stream>>>(h2_pre, batch_idx, meanB, invB, h2_bf, N);

  gemm3<<<N / 16, 256, 0, stream>>>(h2_bf, w3s, y, N);
  stats256_f32<<<512, 256, 0, stream>>>(y, batch_idx, sumC, sqC, N);
  finalize_stats<<<4, 256, 0, stream>>>(sumC, sqC, cnt, meanC, invC, 256);
  final_out<<<2048, 256, 0, stream>>>(y, feats, batch_idx, meanC, invC,
                                      (float*)d_out, N);
}